// Round 1
// baseline (1412.647 us; speedup 1.0000x reference)
//
#include <hip/hip_runtime.h>

namespace {
constexpr int NS  = 16;   // states
constexpr int NC  = 8;    // controls
constexpr int NSC = 24;   // NS + NC
constexpr int TT  = 128;  // horizon

__global__ __launch_bounds__(64)
void lqr_fused_kernel(const float* __restrict__ Qg_,
                      const float* __restrict__ pg_,
                      const float* __restrict__ Fg_,
                      const float* __restrict__ cg_,
                      const float* __restrict__ x0_,
                      float* __restrict__ out)
{
    const int b    = blockIdx.x;
    const int lane = threadIdx.x;

    // persistent gain storage for the whole horizon (fused bwd->fwd)
    __shared__ float Ks[TT][NC][NS];   // 65536 B
    __shared__ float ks[TT][NC];       //  4096 B
    // working set
    __shared__ float Vs[NS][NS + 1];
    __shared__ float vs[NS];
    __shared__ float Fs[NS][NSC + 1];
    __shared__ float Ws[NS][NSC + 1];  // W = V*F, also temp for Vn
    __shared__ float Qh[NSC][NSC + 1];
    __shared__ float qh[NSC];
    __shared__ float zs[NS];
    __shared__ float cs[NS];
    __shared__ float ps[NSC];
    __shared__ float xs[NSC];          // tau during forward

    // V = 0, v = 0
    for (int e = lane; e < NS * NS; e += 64) Vs[e / NS][e % NS] = 0.0f;
    if (lane < NS) vs[lane] = 0.0f;

    const size_t bt0 = (size_t)b * TT;

    // ---- preload t = T-1 into registers ----
    float Freg[6], qreg[9], pcreg;
    {
        const size_t bt = bt0 + (TT - 1);
        const float* Fg  = Fg_ + bt * (NS * NSC);
        const float* Qgp = Qg_ + bt * (NSC * NSC);
        const float* pg  = pg_ + bt * NSC;
        const float* cg  = cg_ + bt * NS;
        #pragma unroll
        for (int r = 0; r < 6; ++r) Freg[r] = Fg[lane + 64 * r];
        #pragma unroll
        for (int r = 0; r < 9; ++r) qreg[r] = Qgp[lane + 64 * r];
        pcreg = 0.0f;
        if (lane < NSC)            pcreg = pg[lane];
        else if (lane < NSC + NS)  pcreg = cg[lane - NSC];
    }

    // ================= backward Riccati scan =================
    for (int t = TT - 1; t >= 0; --t) {
        // commit staged F/p/c to LDS
        #pragma unroll
        for (int r = 0; r < 6; ++r) {
            int e = lane + 64 * r;
            Fs[e / NSC][e % NSC] = Freg[r];
        }
        if (lane < NSC)            ps[lane] = pcreg;
        else if (lane < NSC + NS)  cs[lane - NSC] = pcreg;
        __syncthreads();

        // prefetch F/p/c for t-1 (latency hidden under phases below)
        if (t > 0) {
            const size_t bt = bt0 + (t - 1);
            const float* Fg = Fg_ + bt * (NS * NSC);
            const float* pg = pg_ + bt * NSC;
            const float* cg = cg_ + bt * NS;
            #pragma unroll
            for (int r = 0; r < 6; ++r) Freg[r] = Fg[lane + 64 * r];
            pcreg = 0.0f;
            if (lane < NSC)            pcreg = pg[lane];
            else if (lane < NSC + NS)  pcreg = cg[lane - NSC];
        }

        // Phase A: W[m][j] = sum_n V[n][m]*F[n][j];  z[n] = v[n] + sum_m V[n][m]*c[m]
        #pragma unroll
        for (int r = 0; r < 6; ++r) {
            int e = lane * 6 + r;          // 384 elements, 6 per lane
            int m = e / NSC, j = e % NSC;
            float acc = 0.0f;
            #pragma unroll
            for (int n = 0; n < NS; ++n) acc += Vs[n][m] * Fs[n][j];
            Ws[m][j] = acc;
        }
        if (lane < NS) {
            float acc = vs[lane];
            #pragma unroll
            for (int m = 0; m < NS; ++m) acc += Vs[lane][m] * cs[m];
            zs[lane] = acc;
        }
        __syncthreads();

        // Phase B: Qh = Q + F^T W ; qh = p + F^T z
        #pragma unroll
        for (int r = 0; r < 9; ++r) {
            int e = lane + 64 * r;         // 576 elements, 9 per lane
            int i = e / NSC, j = e % NSC;
            float acc = qreg[r];
            #pragma unroll
            for (int m = 0; m < NS; ++m) acc += Fs[m][i] * Ws[m][j];
            Qh[i][j] = acc;
        }
        if (lane < NSC) {
            float acc = ps[lane];
            #pragma unroll
            for (int n = 0; n < NS; ++n) acc += Fs[n][lane] * zs[n];
            qh[lane] = acc;
        }
        __syncthreads();

        // prefetch Q for t-1 (qreg consumed above; latency hidden under GJ)
        if (t > 0) {
            const float* Qgp = Qg_ + (bt0 + (t - 1)) * (NSC * NSC);
            #pragma unroll
            for (int r = 0; r < 9; ++r) qreg[r] = Qgp[lane + 64 * r];
        }

        // Gauss-Jordan: X = Quu^{-1} [Qux | qu], in place on Qh rows 16..23.
        // Quu >= I (SPD), pivots >= 1 -> no pivoting needed.
        #pragma unroll
        for (int piv = 0; piv < NC; ++piv) {
            float pinv = 1.0f / Qh[NS + piv][NS + piv];
            // scale pivot row: R-part (16 cols + qu) and M-cols piv+1..7
            if (lane < 17) {
                if (lane < NS) Qh[NS + piv][lane] *= pinv;
                else           qh[NS + piv]       *= pinv;
            } else if (lane - 17 < NC - 1 - piv) {
                int c = piv + 1 + (lane - 17);
                Qh[NS + piv][NS + c] *= pinv;
            }
            __syncthreads();
            // eliminate all rows r != piv
            for (int idx = lane; idx < 7 * 24; idx += 64) {
                int rr = idx / 24;
                int r  = rr + (rr >= piv ? 1 : 0);
                int cc = idx % 24;
                float f = Qh[NS + r][NS + piv];
                if (cc < NS) {
                    Qh[NS + r][cc] -= f * Qh[NS + piv][cc];
                } else if (cc == NS) {
                    qh[NS + r] -= f * qh[NS + piv];
                } else {
                    int c = piv + 1 + (cc - 17);
                    if (c < NC) Qh[NS + r][NS + c] -= f * Qh[NS + piv][NS + c];
                }
            }
            __syncthreads();
        }

        // store gains: K = -X[:, :16], k = -X[:,16]
        for (int e = lane; e < NC * NS; e += 64) {
            int c = e / NS, i = e % NS;
            Ks[t][c][i] = -Qh[NS + c][i];
        }
        if (lane < NC) ks[t][lane] = -qh[NS + lane];

        // Vn = Qxx - Qxu*X   (exact equivalent of full formula), vn = qx - Qxu*xq
        #pragma unroll
        for (int r = 0; r < 4; ++r) {
            int e = lane + 64 * r;         // 256 elements, 4 per lane
            int i = e / NS, j = e % NS;
            float acc = Qh[i][j];
            #pragma unroll
            for (int c = 0; c < NC; ++c) acc -= Qh[i][NS + c] * Qh[NS + c][j];
            Ws[i][j] = acc;                // temp
        }
        if (lane < NS) {
            float acc = qh[lane];
            #pragma unroll
            for (int c = 0; c < NC; ++c) acc -= Qh[lane][NS + c] * qh[NS + c];
            zs[lane] = acc;                // temp vn
        }
        __syncthreads();

        // symmetrize into Vs; commit vn
        #pragma unroll
        for (int r = 0; r < 4; ++r) {
            int e = lane + 64 * r;
            int i = e / NS, j = e % NS;
            Vs[i][j] = 0.5f * (Ws[i][j] + Ws[j][i]);
        }
        if (lane < NS) vs[lane] = zs[lane];
        __syncthreads();
    }

    // ================= forward rollout =================
    if (lane < NS) xs[lane] = x0_[(size_t)b * NS + lane];
    float creg = 0.0f;
    {
        const float* Fg = Fg_ + bt0 * (NS * NSC);
        const float* cg = cg_ + bt0 * NS;
        #pragma unroll
        for (int r = 0; r < 6; ++r) Freg[r] = Fg[lane + 64 * r];
        if (lane < NS) creg = cg[lane];
    }
    __syncthreads();

    for (int t = 0; t < TT; ++t) {
        #pragma unroll
        for (int r = 0; r < 6; ++r) {
            int e = lane + 64 * r;
            Fs[e / NSC][e % NSC] = Freg[r];
        }
        if (lane < NS) cs[lane] = creg;
        __syncthreads();

        if (t + 1 < TT) {
            const size_t bt = bt0 + (t + 1);
            const float* Fg = Fg_ + bt * (NS * NSC);
            const float* cg = cg_ + bt * NS;
            #pragma unroll
            for (int r = 0; r < 6; ++r) Freg[r] = Fg[lane + 64 * r];
            if (lane < NS) creg = cg[lane];
        }

        // u = K x + k  -> tau = [x, u]
        if (lane < NC) {
            float acc = ks[t][lane];
            #pragma unroll
            for (int i = 0; i < NS; ++i) acc += Ks[t][lane][i] * xs[i];
            xs[NS + lane] = acc;
        }
        __syncthreads();

        // emit tau; x' = F tau + c
        if (lane < NSC) out[(bt0 + t) * NSC + lane] = xs[lane];
        float xn = 0.0f;
        if (lane < NS) {
            xn = cs[lane];
            #pragma unroll
            for (int j = 0; j < NSC; ++j) xn += Fs[lane][j] * xs[j];
        }
        __syncthreads();
        if (lane < NS) xs[lane] = xn;
        __syncthreads();
    }
}
} // namespace

extern "C" void kernel_launch(void* const* d_in, const int* in_sizes, int n_in,
                              void* d_out, int out_size, void* d_ws, size_t ws_size,
                              hipStream_t stream)
{
    const float* Q  = (const float*)d_in[0];
    const float* p  = (const float*)d_in[1];
    const float* F  = (const float*)d_in[2];
    const float* c1 = (const float*)d_in[3];
    const float* x0 = (const float*)d_in[4];
    float* out = (float*)d_out;

    const int B = in_sizes[4] / NS;   // 512
    lqr_fused_kernel<<<B, 64, 0, stream>>>(Q, p, F, c1, x0, out);
}

// Round 2
// 435.831 us; speedup vs baseline: 3.2413x; 3.2413x over previous
//
#include <hip/hip_runtime.h>

namespace {
constexpr int TT = 128;

__device__ __forceinline__ void wave_sync() {
  // single-wave block: LDS visibility needs only lgkmcnt drain, NOT the
  // vmcnt(0) that __syncthreads would add (which would stall on global
  // prefetches). sched_barrier fences compiler reordering (rule #18).
  asm volatile("s_waitcnt lgkmcnt(0)" ::: "memory");
  __builtin_amdgcn_sched_barrier(0);
}

__device__ __forceinline__ float rdlane(float v, int l) {
  return __int_as_float(__builtin_amdgcn_readlane(__float_as_int(v), l));
}

__global__ __launch_bounds__(64)
void lqr_kernel(const float* __restrict__ Qg, const float* __restrict__ pg,
                const float* __restrict__ Fg, const float* __restrict__ cg,
                const float* __restrict__ x0g, float* __restrict__ out)
{
  // pad 16-wide rows to 20 floats (80B), 24-wide to 28 (112B): keeps b128
  // alignment while breaking power-of-2 bank strides.
  __shared__ __align__(16) float VT[16][20];   // V (symmetric), row j = col j
  __shared__ __align__(16) float vv[16];
  __shared__ __align__(16) float FTx[25][20];  // rows 0..23 = F cols; row 24 = c
  __shared__ __align__(16) float WTx[25][20];  // rows = W^T; row 24 = z
  __shared__ __align__(16) float QhT[25][28];  // rows = Qh^T; row 24 = qh
  __shared__ __align__(16) float Ks[TT][16][8];// KT: Ks[t][j][c] = K[c][j]
  __shared__ __align__(16) float ksv[TT][8];   // k

  const int lane = threadIdx.x;
  const int b = blockIdx.x;
  const size_t bt0 = (size_t)b * TT;

  for (int e = lane; e < 16 * 20; e += 64) (&VT[0][0])[e] = 0.f;
  if (lane < 16) vv[lane] = 0.f;

  const int  pj   = lane >> 1;      // column 0..31 (valid < 25)
  const int  ph   = lane & 1;       // half
  const bool pact = (lane < 50);

  float qreg[12], Freg[6], creg = 0.f;

  // initial prefetch for t = TT-1
  {
    const int t = TT - 1;
    const float* Fs_ = Fg + (bt0 + t) * 384;
    #pragma unroll
    for (int r = 0; r < 6; ++r) Freg[r] = Fs_[lane + 64 * r];
    if (lane >= 48) creg = cg[(bt0 + t) * 16 + (lane - 48)];
    if (pact) {
      if (pj < 24) {
        const float* src = Qg + (bt0 + t) * 576 + pj;
        #pragma unroll
        for (int r = 0; r < 12; ++r) qreg[r] = src[(12 * ph + r) * 24];
      } else {
        const float* src = pg + (bt0 + t) * 24 + 12 * ph;
        #pragma unroll
        for (int r = 0; r < 12; ++r) qreg[r] = src[r];
      }
    }
  }
  wave_sync();

  // ===================== backward Riccati =====================
  for (int t = TT - 1; t >= 0; --t) {
    // commit F^T and c to LDS
    #pragma unroll
    for (int r = 0; r < 6; ++r) { int e = lane + 64 * r; FTx[e % 24][e / 24] = Freg[r]; }
    if (lane >= 48) FTx[24][lane - 48] = creg;
    wave_sync();

    // prefetch next F,c (stays in flight across wave_syncs)
    if (t > 0) {
      const float* Fs_ = Fg + (bt0 + t - 1) * 384;
      #pragma unroll
      for (int r = 0; r < 6; ++r) Freg[r] = Fs_[lane + 64 * r];
      if (lane >= 48) creg = cg[(bt0 + t - 1) * 16 + (lane - 48)];
    }

    // Phase A: WTx[j][m] = sum_n VT[m][n]*FTx[j][n]  (+v bias for j==24)
    if (pact) {
      float fr[16];
      {
        const float4* p4 = (const float4*)&FTx[pj][0];
        float4 a = p4[0], b4 = p4[1], c4 = p4[2], d4 = p4[3];
        fr[0]=a.x; fr[1]=a.y; fr[2]=a.z; fr[3]=a.w;
        fr[4]=b4.x; fr[5]=b4.y; fr[6]=b4.z; fr[7]=b4.w;
        fr[8]=c4.x; fr[9]=c4.y; fr[10]=c4.z; fr[11]=c4.w;
        fr[12]=d4.x; fr[13]=d4.y; fr[14]=d4.z; fr[15]=d4.w;
      }
      float acc[8];
      #pragma unroll
      for (int mi = 0; mi < 8; ++mi) acc[mi] = 0.f;
      if (pj == 24) {
        const float4* p4 = (const float4*)&vv[8 * ph];
        float4 a = p4[0], b4 = p4[1];
        acc[0]=a.x; acc[1]=a.y; acc[2]=a.z; acc[3]=a.w;
        acc[4]=b4.x; acc[5]=b4.y; acc[6]=b4.z; acc[7]=b4.w;
      }
      #pragma unroll
      for (int mi = 0; mi < 8; ++mi) {
        const float4* p4 = (const float4*)&VT[8 * ph + mi][0];
        float4 a = p4[0], b4 = p4[1], c4 = p4[2], d4 = p4[3];
        float s = acc[mi];
        s = fmaf(a.x,  fr[0],  s); s = fmaf(a.y,  fr[1],  s);
        s = fmaf(a.z,  fr[2],  s); s = fmaf(a.w,  fr[3],  s);
        s = fmaf(b4.x, fr[4],  s); s = fmaf(b4.y, fr[5],  s);
        s = fmaf(b4.z, fr[6],  s); s = fmaf(b4.w, fr[7],  s);
        s = fmaf(c4.x, fr[8],  s); s = fmaf(c4.y, fr[9],  s);
        s = fmaf(c4.z, fr[10], s); s = fmaf(c4.w, fr[11], s);
        s = fmaf(d4.x, fr[12], s); s = fmaf(d4.y, fr[13], s);
        s = fmaf(d4.z, fr[14], s); s = fmaf(d4.w, fr[15], s);
        acc[mi] = s;
      }
      float4* wp = (float4*)&WTx[pj][8 * ph];
      wp[0] = make_float4(acc[0], acc[1], acc[2], acc[3]);
      wp[1] = make_float4(acc[4], acc[5], acc[6], acc[7]);
    }
    wave_sync();

    // Phase B: QhT[col][i] = qreg[i] + sum_m FTx[i][m]*WTx[col][m], i = 12*ph+r
    if (pact) {
      float wr[16];
      {
        const float4* p4 = (const float4*)&WTx[pj][0];
        float4 a = p4[0], b4 = p4[1], c4 = p4[2], d4 = p4[3];
        wr[0]=a.x; wr[1]=a.y; wr[2]=a.z; wr[3]=a.w;
        wr[4]=b4.x; wr[5]=b4.y; wr[6]=b4.z; wr[7]=b4.w;
        wr[8]=c4.x; wr[9]=c4.y; wr[10]=c4.z; wr[11]=c4.w;
        wr[12]=d4.x; wr[13]=d4.y; wr[14]=d4.z; wr[15]=d4.w;
      }
      float acc[12];
      #pragma unroll
      for (int r = 0; r < 12; ++r) acc[r] = qreg[r];
      #pragma unroll
      for (int r = 0; r < 12; ++r) {
        const float4* p4 = (const float4*)&FTx[12 * ph + r][0];
        float4 a = p4[0], b4 = p4[1], c4 = p4[2], d4 = p4[3];
        float s = acc[r];
        s = fmaf(a.x,  wr[0],  s); s = fmaf(a.y,  wr[1],  s);
        s = fmaf(a.z,  wr[2],  s); s = fmaf(a.w,  wr[3],  s);
        s = fmaf(b4.x, wr[4],  s); s = fmaf(b4.y, wr[5],  s);
        s = fmaf(b4.z, wr[6],  s); s = fmaf(b4.w, wr[7],  s);
        s = fmaf(c4.x, wr[8],  s); s = fmaf(c4.y, wr[9],  s);
        s = fmaf(c4.z, wr[10], s); s = fmaf(c4.w, wr[11], s);
        s = fmaf(d4.x, wr[12], s); s = fmaf(d4.y, wr[13], s);
        s = fmaf(d4.z, wr[14], s); s = fmaf(d4.w, wr[15], s);
        acc[r] = s;
      }
      float4* qp_ = (float4*)&QhT[pj][12 * ph];
      qp_[0] = make_float4(acc[0], acc[1],  acc[2],  acc[3]);
      qp_[1] = make_float4(acc[4], acc[5],  acc[6],  acc[7]);
      qp_[2] = make_float4(acc[8], acc[9],  acc[10], acc[11]);
    }
    // prefetch next Q,p (qreg now free)
    if (t > 0 && pact) {
      if (pj < 24) {
        const float* src = Qg + (bt0 + t - 1) * 576 + pj;
        #pragma unroll
        for (int r = 0; r < 12; ++r) qreg[r] = src[(12 * ph + r) * 24];
      } else {
        const float* src = pg + (bt0 + t - 1) * 24 + 12 * ph;
        #pragma unroll
        for (int r = 0; r < 12; ++r) qreg[r] = src[r];
      }
    }
    wave_sync();

    // Register Gauss-Jordan: columns of [Quu | Qux | qu], one per lane 0..24.
    float a_[8];
    #pragma unroll
    for (int r = 0; r < 8; ++r) a_[r] = 0.f;
    if (lane < 25) {
      const int row = (lane < 8) ? (16 + lane) : ((lane < 24) ? (lane - 8) : 24);
      const float4* p4 = (const float4*)&QhT[row][16];
      float4 a = p4[0], b4 = p4[1];
      a_[0]=a.x; a_[1]=a.y; a_[2]=a.z; a_[3]=a.w;
      a_[4]=b4.x; a_[5]=b4.y; a_[6]=b4.z; a_[7]=b4.w;
    }
    #pragma unroll
    for (int pp = 0; pp < 8; ++pp) {
      float f[8];
      f[0] = rdlane(a_[0], pp); f[1] = rdlane(a_[1], pp);
      f[2] = rdlane(a_[2], pp); f[3] = rdlane(a_[3], pp);
      f[4] = rdlane(a_[4], pp); f[5] = rdlane(a_[5], pp);
      f[6] = rdlane(a_[6], pp); f[7] = rdlane(a_[7], pp);
      float r0 = __builtin_amdgcn_rcpf(f[pp]);
      float d  = r0 * (2.0f - f[pp] * r0);   // Newton refine
      a_[pp] *= d;
      #pragma unroll
      for (int r = 0; r < 8; ++r)
        if (r != pp) a_[r] = fmaf(-f[r], a_[pp], a_[r]);
    }

    // commit gains: lane 8+j holds X[:,j]; K = -X, k = -xq
    if (lane >= 8 && lane < 25) {
      float4 k0 = make_float4(-a_[0], -a_[1], -a_[2], -a_[3]);
      float4 k1 = make_float4(-a_[4], -a_[5], -a_[6], -a_[7]);
      float4* kp = (lane < 24) ? (float4*)&Ks[t][lane - 8][0] : (float4*)&ksv[t][0];
      kp[0] = k0; kp[1] = k1;
    }

    // Vn col j = Qxx col j - Qxu * X[:,j]   (lane 24: vn = qx - Qxu*xq)
    if (lane >= 8 && lane < 25) {
      const int j   = lane - 8;
      const int row = (j < 16) ? j : 24;
      float acc[16];
      {
        const float4* p4 = (const float4*)&QhT[row][0];
        float4 a = p4[0], b4 = p4[1], c4 = p4[2], d4 = p4[3];
        acc[0]=a.x;  acc[1]=a.y;  acc[2]=a.z;  acc[3]=a.w;
        acc[4]=b4.x; acc[5]=b4.y; acc[6]=b4.z; acc[7]=b4.w;
        acc[8]=c4.x; acc[9]=c4.y; acc[10]=c4.z; acc[11]=c4.w;
        acc[12]=d4.x; acc[13]=d4.y; acc[14]=d4.z; acc[15]=d4.w;
      }
      #pragma unroll
      for (int c = 0; c < 8; ++c) {
        const float4* p4 = (const float4*)&QhT[16 + c][0];
        float4 q0 = p4[0], q1 = p4[1], q2 = p4[2], q3 = p4[3];
        const float s = a_[c];
        acc[0]  = fmaf(-s, q0.x, acc[0]);  acc[1]  = fmaf(-s, q0.y, acc[1]);
        acc[2]  = fmaf(-s, q0.z, acc[2]);  acc[3]  = fmaf(-s, q0.w, acc[3]);
        acc[4]  = fmaf(-s, q1.x, acc[4]);  acc[5]  = fmaf(-s, q1.y, acc[5]);
        acc[6]  = fmaf(-s, q1.z, acc[6]);  acc[7]  = fmaf(-s, q1.w, acc[7]);
        acc[8]  = fmaf(-s, q2.x, acc[8]);  acc[9]  = fmaf(-s, q2.y, acc[9]);
        acc[10] = fmaf(-s, q2.z, acc[10]); acc[11] = fmaf(-s, q2.w, acc[11]);
        acc[12] = fmaf(-s, q3.x, acc[12]); acc[13] = fmaf(-s, q3.y, acc[13]);
        acc[14] = fmaf(-s, q3.z, acc[14]); acc[15] = fmaf(-s, q3.w, acc[15]);
      }
      float4* vp_ = (j < 16) ? (float4*)&VT[j][0] : (float4*)&vv[0];
      vp_[0] = make_float4(acc[0],  acc[1],  acc[2],  acc[3]);
      vp_[1] = make_float4(acc[4],  acc[5],  acc[6],  acc[7]);
      vp_[2] = make_float4(acc[8],  acc[9],  acc[10], acc[11]);
      vp_[3] = make_float4(acc[12], acc[13], acc[14], acc[15]);
    }
    wave_sync();
  }

  // ===================== forward rollout =====================
  float xv = (lane < 16) ? x0g[(size_t)b * 16 + lane] : 0.f;
  float xs_[16];
  #pragma unroll
  for (int i = 0; i < 16; ++i) xs_[i] = rdlane(xv, i);

  float FA[24], FB[24];
  float cA = 0.f, cB = 0.f;

  auto loadF = [&](int t, float (&Fr)[24], float& cr) {
    if (lane < 16) {
      const float* src = Fg + (bt0 + t) * 384 + lane * 24;
      #pragma unroll
      for (int r = 0; r < 6; ++r) {
        float4 f4v = ((const float4*)src)[r];
        Fr[4*r+0] = f4v.x; Fr[4*r+1] = f4v.y; Fr[4*r+2] = f4v.z; Fr[4*r+3] = f4v.w;
      }
      cr = cg[(bt0 + t) * 16 + lane];
    }
  };

  auto fstep = [&](int t, const float (&Fr)[24], float cr) {
    float uv = 0.f;
    if (lane < 8) {
      uv = ksv[t][lane];
      #pragma unroll
      for (int i = 0; i < 16; ++i) uv = fmaf(Ks[t][i][lane], xs_[i], uv);
    }
    float us[8];
    #pragma unroll
    for (int c = 0; c < 8; ++c) us[c] = rdlane(uv, c);
    float* o = out + (bt0 + t) * 24;
    if (lane < 16) o[lane] = xv;
    if (lane < 8)  o[16 + lane] = uv;
    float xn = cr;
    #pragma unroll
    for (int j2 = 0; j2 < 16; ++j2) xn = fmaf(Fr[j2], xs_[j2], xn);
    #pragma unroll
    for (int c = 0; c < 8; ++c) xn = fmaf(Fr[16 + c], us[c], xn);
    xv = xn;
    #pragma unroll
    for (int i = 0; i < 16; ++i) xs_[i] = rdlane(xv, i);
  };

  loadF(0, FA, cA);
  for (int t = 0; t < TT; t += 2) {
    if (t + 1 < TT) loadF(t + 1, FB, cB);
    fstep(t, FA, cA);
    if (t + 2 < TT) loadF(t + 2, FA, cA);
    fstep(t + 1, FB, cB);
  }
}
} // namespace

extern "C" void kernel_launch(void* const* d_in, const int* in_sizes, int n_in,
                              void* d_out, int out_size, void* d_ws, size_t ws_size,
                              hipStream_t stream)
{
  (void)n_in; (void)out_size; (void)d_ws; (void)ws_size;
  const float* Q  = (const float*)d_in[0];
  const float* p  = (const float*)d_in[1];
  const float* F  = (const float*)d_in[2];
  const float* c1 = (const float*)d_in[3];
  const float* x0 = (const float*)d_in[4];
  float* out = (float*)d_out;

  const int B = in_sizes[4] / 16;   // 512
  lqr_kernel<<<B, 64, 0, stream>>>(Q, p, F, c1, x0, out);
}

// Round 3
// 324.033 us; speedup vs baseline: 4.3596x; 1.3450x over previous
//
#include <hip/hip_runtime.h>

namespace {
constexpr int TT = 128;

__device__ __forceinline__ float rdlane(float v, int l) {
  return __int_as_float(__builtin_amdgcn_readlane(__float_as_int(v), l));
}

__device__ __forceinline__ void bsync() {
  // 256-thread barrier WITHOUT vmcnt drain: global prefetches stay in flight.
  asm volatile("s_waitcnt lgkmcnt(0)" ::: "memory");
  __builtin_amdgcn_s_barrier();
  asm volatile("" ::: "memory");
  __builtin_amdgcn_sched_barrier(0);
}

__global__ __launch_bounds__(256)
void lqr_kernel(const float* __restrict__ Qg, const float* __restrict__ pg,
                const float* __restrict__ Fg, const float* __restrict__ cg,
                const float* __restrict__ x0g, float* __restrict__ out)
{
  // Quad-XOR-swizzled tiles: element (row, n) lives at
  //   row*STRIDE + ((n>>2 ^ ((row>>2)&3))<<2) + (n&3)
  __shared__ __align__(16) float VT[16][20];     // plain; V columns (symmetric)
  __shared__ __align__(16) float vv[16];
  __shared__ __align__(16) float FTxd[2][25][20];// swz; rows 0..23=F cols, 24=c
  __shared__ __align__(16) float WTx[25][20];    // swz; rows=W^T cols, 24=z
  __shared__ __align__(16) float QhT[25][36];    // swz; rows=Qh cols, 24=qh
  __shared__ __align__(16) float Ks[TT][16][8];  // Ks[t][j][c] = K[c][j]
  __shared__ __align__(16) float ksv[TT][8];

  const int tid  = threadIdx.x;
  const int lane = tid & 63;
  const int wv   = tid >> 6;
  const int b    = blockIdx.x;
  const size_t bt0 = (size_t)b * TT;

  const int jl = tid & 31;   // per-lane column index (valid <25 / <24)
  const int g  = tid >> 5;   // 0..7, uniform per half-wave

  // zero V, v
  if (tid < 320) (&VT[0][0])[tid] = 0.f;
  if (tid < 64) (&VT[0][0])[tid + 256] = 0.f;   // 256..319
  if (tid < 16) vv[tid] = 0.f;

  float Freg[3] = {0.f, 0.f, 0.f};
  float qreg[3] = {0.f, 0.f, 0.f}, qreg3 = 0.f;

  // waves 1..3 stage F/c (192 threads, 400 elements)
  auto loadF = [&](int t) {
    if (wv > 0) {
      const float* Fs = Fg + (bt0 + t) * 384;
      const int e0 = tid - 64;
      #pragma unroll
      for (int r = 0; r < 3; ++r) {
        const int e = e0 + 192 * r;
        if (e < 384)      Freg[r] = Fs[e];
        else if (e < 400) Freg[r] = cg[(bt0 + t) * 16 + (e - 384)];
      }
    }
  };
  auto commitF = [&](int buf) {
    if (wv > 0) {
      float* F0 = &FTxd[buf][0][0];
      const int e0 = tid - 64;
      #pragma unroll
      for (int r = 0; r < 3; ++r) {
        const int e = e0 + 192 * r;
        if (e < 384) {
          const int j = e % 24, n = e / 24;
          F0[j * 20 + ((((n >> 2) ^ ((j >> 2) & 3)) << 2) + (n & 3))] = Freg[r];
        } else if (e < 400) {
          const int n = e - 384;                 // row 24, s = 2
          F0[24 * 20 + ((((n >> 2) ^ 2) << 2) + (n & 3))] = Freg[r];
        }
      }
    }
  };
  auto loadQ = [&](int t) {
    if (jl < 24) {
      const float* Qs = Qg + (bt0 + t) * 576;
      #pragma unroll
      for (int r = 0; r < 3; ++r) qreg[r] = Qs[(3 * g + r) * 24 + jl]; // Q sym
      if (g == 7) qreg3 = pg[(bt0 + t) * 24 + jl];
    }
  };

  // ---- prologue ----
  loadF(TT - 1);
  loadQ(TT - 1);
  commitF((TT - 1) & 1);
  loadF(TT - 2);
  bsync();

  // ===================== backward Riccati =====================
  for (int t = TT - 1; t >= 0; --t) {
    const float* Fb = &FTxd[t & 1][0][0];

    // Phase A: WTx[j][m] = sum_n V[m][n] * F[n][j]  (+v for j==24 -> z)
    float fr[16];
    if (jl < 25) {
      const int sj = (jl >> 2) & 3;
      const float* fb = Fb + jl * 20;
      #pragma unroll
      for (int q = 0; q < 4; ++q) {
        float4 v4 = *(const float4*)(fb + ((q ^ sj) << 2));
        fr[4*q+0] = v4.x; fr[4*q+1] = v4.y; fr[4*q+2] = v4.z; fr[4*q+3] = v4.w;
      }
      const int m0 = 2 * g, m1 = m0 + 1;
      float acc0 = (jl == 24) ? vv[m0] : 0.f;
      float acc1 = (jl == 24) ? vv[m1] : 0.f;
      #pragma unroll
      for (int q = 0; q < 4; ++q) {
        float4 a0 = *(const float4*)(&VT[m0][4*q]);   // broadcast per half-wave
        float4 a1 = *(const float4*)(&VT[m1][4*q]);
        acc0 = fmaf(a0.x, fr[4*q+0], acc0); acc0 = fmaf(a0.y, fr[4*q+1], acc0);
        acc0 = fmaf(a0.z, fr[4*q+2], acc0); acc0 = fmaf(a0.w, fr[4*q+3], acc0);
        acc1 = fmaf(a1.x, fr[4*q+0], acc1); acc1 = fmaf(a1.y, fr[4*q+1], acc1);
        acc1 = fmaf(a1.z, fr[4*q+2], acc1); acc1 = fmaf(a1.w, fr[4*q+3], acc1);
      }
      float* wb = &WTx[0][0] + jl * 20;
      *(float2*)(wb + ((((g >> 1) ^ sj) << 2) + (m0 & 3))) = make_float2(acc0, acc1);
    }
    bsync();

    // Phase B: QhT[c][i] = Qsrc + sum_m F[m][i] * W[m][c]   (i = jl)
    if (jl < 24) {
      #pragma unroll
      for (int r = 0; r < 3; ++r) {
        const int c = 3 * g + r;
        const int sc = (c >> 2) & 3;
        const float* wb = &WTx[0][0] + c * 20;   // broadcast per half-wave
        float acc = qreg[r];
        #pragma unroll
        for (int q = 0; q < 4; ++q) {
          float4 w4 = *(const float4*)(wb + ((q ^ sc) << 2));
          acc = fmaf(w4.x, fr[4*q+0], acc); acc = fmaf(w4.y, fr[4*q+1], acc);
          acc = fmaf(w4.z, fr[4*q+2], acc); acc = fmaf(w4.w, fr[4*q+3], acc);
        }
        float* qb = &QhT[0][0] + c * 36;
        qb[(((jl >> 2) ^ sc) << 2) + (jl & 3)] = acc;
      }
      if (g == 7) {                               // qh row (c==24), s=2
        const float* wb = &WTx[0][0] + 24 * 20;
        float acc = qreg3;
        #pragma unroll
        for (int q = 0; q < 4; ++q) {
          float4 w4 = *(const float4*)(wb + ((q ^ 2) << 2));
          acc = fmaf(w4.x, fr[4*q+0], acc); acc = fmaf(w4.y, fr[4*q+1], acc);
          acc = fmaf(w4.z, fr[4*q+2], acc); acc = fmaf(w4.w, fr[4*q+3], acc);
        }
        float* qb = &QhT[0][0] + 24 * 36;
        qb[(((jl >> 2) ^ 2) << 2) + (jl & 3)] = acc;
      }
    }
    if (t > 0) loadQ(t - 1);
    bsync();

    // GJ + gains + V-update on wave 0; waves 1..3 commit next F tile.
    if (wv == 0) {
      float a_[8];
      #pragma unroll
      for (int r = 0; r < 8; ++r) a_[r] = 0.f;
      if (lane < 25) {
        const int row = (lane < 8) ? (16 + lane) : ((lane < 24) ? (lane - 8) : 24);
        const int s = (row >> 2) & 3;
        const float* base = &QhT[0][0] + row * 36;
        float4 x0v = *(const float4*)(base + ((4 ^ s) << 2));
        float4 x1v = *(const float4*)(base + ((5 ^ s) << 2));
        a_[0]=x0v.x; a_[1]=x0v.y; a_[2]=x0v.z; a_[3]=x0v.w;
        a_[4]=x1v.x; a_[5]=x1v.y; a_[6]=x1v.z; a_[7]=x1v.w;
      }
      #pragma unroll
      for (int pp = 0; pp < 8; ++pp) {
        float f_[8];
        f_[0] = rdlane(a_[0], pp); f_[1] = rdlane(a_[1], pp);
        f_[2] = rdlane(a_[2], pp); f_[3] = rdlane(a_[3], pp);
        f_[4] = rdlane(a_[4], pp); f_[5] = rdlane(a_[5], pp);
        f_[6] = rdlane(a_[6], pp); f_[7] = rdlane(a_[7], pp);
        float r0 = __builtin_amdgcn_rcpf(f_[pp]);
        float d  = r0 * (2.0f - f_[pp] * r0);       // Quu >= I: pivot safe
        a_[pp] *= d;
        #pragma unroll
        for (int r = 0; r < 8; ++r)
          if (r != pp) a_[r] = fmaf(-f_[r], a_[pp], a_[r]);
      }
      if (lane >= 8 && lane < 25) {
        float4 k0 = make_float4(-a_[0], -a_[1], -a_[2], -a_[3]);
        float4 k1 = make_float4(-a_[4], -a_[5], -a_[6], -a_[7]);
        float4* kp = (lane < 24) ? (float4*)&Ks[t][lane - 8][0] : (float4*)&ksv[t][0];
        kp[0] = k0; kp[1] = k1;

        const int j = lane - 8;
        const int row = (j < 16) ? j : 24;
        const int s = (row >> 2) & 3;
        const float* base = &QhT[0][0] + row * 36;
        float acc[16];
        #pragma unroll
        for (int q = 0; q < 4; ++q) {
          float4 v4 = *(const float4*)(base + ((q ^ s) << 2));
          acc[4*q+0]=v4.x; acc[4*q+1]=v4.y; acc[4*q+2]=v4.z; acc[4*q+3]=v4.w;
        }
        #pragma unroll
        for (int c = 0; c < 8; ++c) {
          const int s2 = ((16 + c) >> 2) & 3;       // compile-time 0 or 1
          const float* qb = &QhT[0][0] + (16 + c) * 36;
          float4 q0 = *(const float4*)(qb + ((0 ^ s2) << 2));
          float4 q1 = *(const float4*)(qb + ((1 ^ s2) << 2));
          float4 q2 = *(const float4*)(qb + ((2 ^ s2) << 2));
          float4 q3 = *(const float4*)(qb + ((3 ^ s2) << 2));
          const float sc_ = a_[c];
          acc[0]  = fmaf(-sc_, q0.x, acc[0]);  acc[1]  = fmaf(-sc_, q0.y, acc[1]);
          acc[2]  = fmaf(-sc_, q0.z, acc[2]);  acc[3]  = fmaf(-sc_, q0.w, acc[3]);
          acc[4]  = fmaf(-sc_, q1.x, acc[4]);  acc[5]  = fmaf(-sc_, q1.y, acc[5]);
          acc[6]  = fmaf(-sc_, q1.z, acc[6]);  acc[7]  = fmaf(-sc_, q1.w, acc[7]);
          acc[8]  = fmaf(-sc_, q2.x, acc[8]);  acc[9]  = fmaf(-sc_, q2.y, acc[9]);
          acc[10] = fmaf(-sc_, q2.z, acc[10]); acc[11] = fmaf(-sc_, q2.w, acc[11]);
          acc[12] = fmaf(-sc_, q3.x, acc[12]); acc[13] = fmaf(-sc_, q3.y, acc[13]);
          acc[14] = fmaf(-sc_, q3.z, acc[14]); acc[15] = fmaf(-sc_, q3.w, acc[15]);
        }
        float4* vp = (j < 16) ? (float4*)&VT[j][0] : (float4*)&vv[0];
        vp[0] = make_float4(acc[0],  acc[1],  acc[2],  acc[3]);
        vp[1] = make_float4(acc[4],  acc[5],  acc[6],  acc[7]);
        vp[2] = make_float4(acc[8],  acc[9],  acc[10], acc[11]);
        vp[3] = make_float4(acc[12], acc[13], acc[14], acc[15]);
      }
    } else {
      if (t > 0) commitF((t - 1) & 1);
      if (t > 1) loadF(t - 2);
    }
    bsync();
  }

  // ===================== forward rollout (wave 0) =====================
  if (wv == 0) {
    float xv = (lane < 16) ? x0g[(size_t)b * 16 + lane] : 0.f;
    float xs_[16];
    #pragma unroll
    for (int i = 0; i < 16; ++i) xs_[i] = rdlane(xv, i);

    float FA[24], FB[24];
    float cA = 0.f, cB = 0.f;

    auto loadFw = [&](int t, float (&Fr)[24], float& cr) {
      if (lane < 16) {
        const float* src = Fg + (bt0 + t) * 384 + lane * 24;
        #pragma unroll
        for (int r = 0; r < 6; ++r) {
          float4 f4v = ((const float4*)src)[r];
          Fr[4*r+0] = f4v.x; Fr[4*r+1] = f4v.y; Fr[4*r+2] = f4v.z; Fr[4*r+3] = f4v.w;
        }
        cr = cg[(bt0 + t) * 16 + lane];
      }
    };

    auto fstep = [&](int t, const float (&Fr)[24], float cr) {
      float uv = 0.f;
      if (lane < 8) {
        uv = ksv[t][lane];
        #pragma unroll
        for (int i = 0; i < 16; ++i) uv = fmaf(Ks[t][i][lane], xs_[i], uv);
      }
      float us[8];
      #pragma unroll
      for (int c = 0; c < 8; ++c) us[c] = rdlane(uv, c);
      float* o = out + (bt0 + t) * 24;
      if (lane < 16) o[lane] = xv;
      if (lane < 8)  o[16 + lane] = uv;
      float xn = cr;
      #pragma unroll
      for (int j2 = 0; j2 < 16; ++j2) xn = fmaf(Fr[j2], xs_[j2], xn);
      #pragma unroll
      for (int c = 0; c < 8; ++c) xn = fmaf(Fr[16 + c], us[c], xn);
      xv = xn;
      #pragma unroll
      for (int i = 0; i < 16; ++i) xs_[i] = rdlane(xv, i);
    };

    loadFw(0, FA, cA);
    for (int t = 0; t < TT; t += 2) {
      if (t + 1 < TT) loadFw(t + 1, FB, cB);
      fstep(t, FA, cA);
      if (t + 2 < TT) loadFw(t + 2, FA, cA);
      fstep(t + 1, FB, cB);
    }
  }
}
} // namespace

extern "C" void kernel_launch(void* const* d_in, const int* in_sizes, int n_in,
                              void* d_out, int out_size, void* d_ws, size_t ws_size,
                              hipStream_t stream)
{
  (void)n_in; (void)out_size; (void)d_ws; (void)ws_size;
  const float* Q  = (const float*)d_in[0];
  const float* p  = (const float*)d_in[1];
  const float* F  = (const float*)d_in[2];
  const float* c1 = (const float*)d_in[3];
  const float* x0 = (const float*)d_in[4];
  float* outp = (float*)d_out;

  const int B = in_sizes[4] / 16;   // 512
  lqr_kernel<<<B, 256, 0, stream>>>(Q, p, F, c1, x0, outp);
}